// Round 1
// baseline (2033.381 us; speedup 1.0000x reference)
//
#include <hip/hip_runtime.h>

#define DTC 0.02f
#define INV_DT_SKIP (1.0f / 0.4f)   // DT_SKIP = 0.02*20 = 0.4
#define NGH 8000
#define NGT 16000
#define NRHS 250                    // rhs blocks; 250*64 = 16000 groups
#define GPB 64                      // groups per rhs block

// ---------------------------------------------------------------------------
// Inverses of mat_1st = I - dt*Ap  and  mat_2nd = 3I - 2dt*Ap via Neumann:
// (I-E)^-1 = I+E+E^2+E^3+E^4,  E = dt*Ap  (||E|| ~ 0.016)
// mat_2nd^-1 = (1/3)(I-E2)^-1, E2 = (2dt/3)*Ap
// block 0 -> inv1, block 1 -> inv2. Horner: X <- I + E@X, 3 times from X=I+E.
// ---------------------------------------------------------------------------
__global__ __launch_bounds__(256) void kinv(const float* __restrict__ Ap,
                                            float* __restrict__ inv1,
                                            float* __restrict__ inv2) {
    const int t = threadIdx.x;
    const float coef  = (blockIdx.x == 0) ? DTC : (2.0f * DTC / 3.0f);
    const float scale = (blockIdx.x == 0) ? 1.0f : (1.0f / 3.0f);
    float* outp = (blockIdx.x == 0) ? inv1 : inv2;

    __shared__ float ET[64 * 68];   // E transposed, padded (bank-conflict-free)
    __shared__ float XA[64 * 68];
    __shared__ float XB[64 * 68];

    for (int idx = t; idx < 4096; idx += 256) {
        int r = idx >> 6, c = idx & 63;
        float e = coef * Ap[idx];
        ET[c * 68 + r] = e;
        XA[r * 68 + c] = ((r == c) ? 1.0f : 0.0f) + e;   // X = I + E
    }
    __syncthreads();

    const int rr = (t >> 4) << 2;   // 4x4 output tile per thread
    const int cc = (t & 15) << 2;
    float* bufs[2] = {XA, XB};
    for (int it = 0; it < 3; it++) {
        const float* Xin = bufs[it & 1];
        float* Xout = bufs[(it + 1) & 1];
        float acc[4][4];
        #pragma unroll
        for (int i = 0; i < 4; i++)
            #pragma unroll
            for (int j = 0; j < 4; j++)
                acc[i][j] = ((rr + i) == (cc + j)) ? 1.0f : 0.0f;
        for (int k = 0; k < 64; k++) {
            float4 e4 = *(const float4*)&ET[k * 68 + rr];
            float4 x4 = *(const float4*)&Xin[k * 68 + cc];
            float ev[4] = {e4.x, e4.y, e4.z, e4.w};
            float xv[4] = {x4.x, x4.y, x4.z, x4.w};
            #pragma unroll
            for (int i = 0; i < 4; i++)
                #pragma unroll
                for (int j = 0; j < 4; j++)
                    acc[i][j] += ev[i] * xv[j];
        }
        __syncthreads();            // readers of Xout's old content are done
        #pragma unroll
        for (int i = 0; i < 4; i++)
            #pragma unroll
            for (int j = 0; j < 4; j++)
                Xout[(rr + i) * 68 + cc + j] = acc[i][j];
        __syncthreads();
    }
    const float* Xf = bufs[1];      // after 3 Horner steps result is in XB
    for (int idx = t; idx < 4096; idx += 256) {
        int r = idx >> 6, c = idx & 63;
        outp[idx] = scale * Xf[r * 68 + c];
    }
}

// ---------------------------------------------------------------------------
// rhs split-K: block handles 64 groups; thread (b = t&31, gi = t>>5) computes
// the full 4 dots (u,v,dx,dy) for its (batch, group) against a-row held in
// registers; W read directly from global (32 lanes broadcast-coalesce to 2
// distinct 16B addresses per instruction). f exchanged via LDS, then rank-1
// accumulate into per-thread acc[4] (p = gi*4+kk). Partials -> ws (NO sign
// flip here; kupd negates).
// ---------------------------------------------------------------------------
__global__ __launch_bounds__(512) void krhs(const float* __restrict__ a,
                                            const float* __restrict__ Wu,
                                            const float* __restrict__ Wv,
                                            const float* __restrict__ Pp,
                                            float* __restrict__ partials) {
    const int t  = threadIdx.x;
    const int b  = t & 31;
    const int gi = t >> 5;          // 0..15: 16 groups in flight per round
    const int blk = blockIdx.x;
    const bool isv = (blk >= 125);  // blocks 0..124 -> u net, 125..249 -> v net
    const float* W = isv ? Wv : Wu;
    const int gnet0  = (isv ? (blk - 125) : blk) * GPB; // net-local group base
    const int gglob0 = blk * GPB;                        // global group base

    float ar[64];
    {
        const float4* a4 = (const float4*)(a + b * 64);
        float4* ar4 = (float4*)ar;
        #pragma unroll
        for (int i = 0; i < 16; i++) ar4[i] = a4[i];
    }

    __shared__ float fsh[16][33];
    float acc[4] = {0.f, 0.f, 0.f, 0.f};

    for (int r = 0; r < 4; r++) {           // 4 rounds x 16 groups = 64
        const int g = gnet0 + r * 16 + gi;
        const float* w0 = W + (size_t)g * 64;            // u row
        const float* w1 = w0 + (size_t)NGH * 64;         // v row
        const float* w2 = w1 + (size_t)NGH * 64;         // dx row
        const float* w3 = w2 + (size_t)NGH * 64;         // dy row
        float s0 = 0.f, s1 = 0.f, s2 = 0.f, s3 = 0.f;
        #pragma unroll
        for (int k = 0; k < 64; k += 4) {
            float4 x0 = *(const float4*)(w0 + k);
            float4 x1 = *(const float4*)(w1 + k);
            float4 x2 = *(const float4*)(w2 + k);
            float4 x3 = *(const float4*)(w3 + k);
            s0 += x0.x*ar[k] + x0.y*ar[k+1] + x0.z*ar[k+2] + x0.w*ar[k+3];
            s1 += x1.x*ar[k] + x1.y*ar[k+1] + x1.z*ar[k+2] + x1.w*ar[k+3];
            s2 += x2.x*ar[k] + x2.y*ar[k+1] + x2.z*ar[k+2] + x2.w*ar[k+3];
            s3 += x3.x*ar[k] + x3.y*ar[k+1] + x3.z*ar[k+2] + x3.w*ar[k+3];
        }
        float f = s0 * s2 + s1 * s3;        // u*dx + v*dy
        __syncthreads();                    // WAR protection across rounds
        fsh[gi][b] = f;
        __syncthreads();
        float fv[16];
        #pragma unroll
        for (int j = 0; j < 16; j++) fv[j] = fsh[j][b];
        const int gg = gglob0 + r * 16;
        #pragma unroll
        for (int kk = 0; kk < 4; kk++) {
            const int p = gi * 4 + kk;      // this thread's output columns
            const float* prow = Pp + (size_t)p * NGT + gg;
            float4 pa = *(const float4*)(prow);
            float4 pb = *(const float4*)(prow + 4);
            float4 pc = *(const float4*)(prow + 8);
            float4 pd = *(const float4*)(prow + 12);
            acc[kk] += pa.x*fv[0]  + pa.y*fv[1]  + pa.z*fv[2]  + pa.w*fv[3]
                     + pb.x*fv[4]  + pb.y*fv[5]  + pb.z*fv[6]  + pb.w*fv[7]
                     + pc.x*fv[8]  + pc.y*fv[9]  + pc.z*fv[10] + pc.w*fv[11]
                     + pd.x*fv[12] + pd.y*fv[13] + pd.z*fv[14] + pd.w*fv[15];
        }
    }
    *(float4*)(partials + (size_t)blk * 2048 + b * 64 + gi * 4) =
        make_float4(acc[0], acc[1], acc[2], acc[3]);
}

// ---------------------------------------------------------------------------
// Reduce split-K partials -> f_k (negated), BDF2/Euler combine, 64x64 matvec
// with precomputed inverse, write a_{k+1}; final step also writes output.
// One block per batch row. 512 threads: p = t&63, q = t>>6 (8-way split-K).
// ---------------------------------------------------------------------------
__global__ __launch_bounds__(512) void kupd(const float* __restrict__ partials,
                                            const float* __restrict__ invm,
                                            const float* __restrict__ a_new,
                                            const float* __restrict__ a_prev,
                                            const float* __restrict__ fprev,
                                            float* __restrict__ fout,
                                            float* __restrict__ a_out,
                                            const float* __restrict__ state,
                                            float* __restrict__ out,
                                            int first, int last) {
    const int bb = blockIdx.x;
    const int t = threadIdx.x;
    const int p = t & 63;
    const int q = t >> 6;   // 0..7
    float s = 0.f;
    for (int m = q; m < NRHS; m += 8)
        s += partials[(size_t)m * 2048 + bb * 64 + p];
    __shared__ float red[512];
    __shared__ float rrow[64];
    red[t] = s;
    __syncthreads();
    if (t < 64) {
        float f = 0.f;
        #pragma unroll
        for (int j = 0; j < 8; j++) f += red[j * 64 + t];
        f = -f;                              // rhs sign
        fout[bb * 64 + t] = f;
        float rv;
        if (first) rv = a_new[bb * 64 + t] + DTC * f;
        else       rv = 4.0f * a_new[bb * 64 + t] - a_prev[bb * 64 + t]
                      + 4.0f * DTC * f - 2.0f * DTC * fprev[bb * 64 + t];
        rrow[t] = rv;
    }
    __syncthreads();
    // a_next[b][p] = sum_k inv[p][k] * r[k]
    float acc = 0.f;
    const float* ivr = invm + p * 64 + q * 8;
    #pragma unroll
    for (int kk = 0; kk < 8; kk++) acc += ivr[kk] * rrow[q * 8 + kk];
    red[t] = acc;
    __syncthreads();
    if (t < 64) {
        float an = 0.f;
        #pragma unroll
        for (int j = 0; j < 8; j++) an += red[j * 64 + t];
        a_out[bb * 64 + t] = an;
        if (last) out[bb * 64 + t] = (an - state[bb * 64 + t]) * INV_DT_SKIP;
    }
}

// ---------------------------------------------------------------------------
extern "C" void kernel_launch(void* const* d_in, const int* in_sizes, int n_in,
                              void* d_out, int out_size, void* d_ws, size_t ws_size,
                              hipStream_t stream) {
    const float* state = (const float*)d_in[0];   // (32, 64)
    const float* Ap    = (const float*)d_in[1];   // (64, 64)
    const float* Wu    = (const float*)d_in[2];   // (32000, 64)
    const float* Wv    = (const float*)d_in[3];   // (32000, 64)
    const float* Pp    = (const float*)d_in[4];   // (64, 16000)
    float* out = (float*)d_out;
    float* ws  = (float*)d_ws;

    float* inv1 = ws;                         // 4096
    float* inv2 = ws + 4096;                  // 4096
    float* abuf = ws + 8192;                  // 3 * 2048 (a rotation)
    float* fbuf = ws + 8192 + 3 * 2048;       // 2 * 2048 (f ping-pong)
    float* partials = ws + 8192 + 5 * 2048;   // 250 * 2048

    hipLaunchKernelGGL(kinv, dim3(2), dim3(256), 0, stream, Ap, inv1, inv2);

    const float* aptr[51];
    aptr[0] = state;
    for (int k = 1; k <= 50; k++) aptr[k] = abuf + (size_t)((k - 1) % 3) * 2048;

    for (int k = 0; k < 50; k++) {
        hipLaunchKernelGGL(krhs, dim3(NRHS), dim3(512), 0, stream,
                           aptr[k], Wu, Wv, Pp, partials);
        hipLaunchKernelGGL(kupd, dim3(32), dim3(512), 0, stream,
                           partials,
                           (k == 0) ? inv1 : inv2,
                           aptr[k],                        // a_new = a_k
                           (k >= 1) ? aptr[k - 1] : state, // a_prev (unused k=0)
                           fbuf + (size_t)((k + 1) & 1) * 2048, // f_prev
                           fbuf + (size_t)(k & 1) * 2048,       // f_out
                           (float*)aptr[k + 1],            // a_{k+1}
                           state, out,
                           (k == 0) ? 1 : 0,
                           (k == 49) ? 1 : 0);
    }
}

// Round 2
// 905.883 us; speedup vs baseline: 2.2446x; 2.2446x over previous
//
#include <hip/hip_runtime.h>

#define DTC 0.02f
#define INV_DT_SKIP (1.0f / 0.4f)   // DT_SKIP = 0.02*20 = 0.4
#define NRHS 250                    // partial buffers (one per krhs block)

typedef __attribute__((ext_vector_type(8))) __bf16 bf16x8;
typedef __attribute__((ext_vector_type(4))) float f32x4;
typedef __attribute__((ext_vector_type(8))) unsigned short us8;

__device__ inline unsigned short f2bf(float x) {        // RNE fp32->bf16
    unsigned u = __float_as_uint(x);
    unsigned r = u + 0x7FFF + ((u >> 16) & 1u);
    return (unsigned short)(r >> 16);
}
__device__ inline float bf2f(unsigned short h) {
    return __uint_as_float(((unsigned)h) << 16);
}

// ---------------------------------------------------------------------------
// Inverses of mat_1st = I - dt*Ap and mat_2nd = 3I - 2dt*Ap via 4-term
// Neumann/Horner (||E|| ~ 0.016). Unchanged from round 1 (verified).
// ---------------------------------------------------------------------------
__global__ __launch_bounds__(256) void kinv(const float* __restrict__ Ap,
                                            float* __restrict__ inv1,
                                            float* __restrict__ inv2) {
    const int t = threadIdx.x;
    const float coef  = (blockIdx.x == 0) ? DTC : (2.0f * DTC / 3.0f);
    const float scale = (blockIdx.x == 0) ? 1.0f : (1.0f / 3.0f);
    float* outp = (blockIdx.x == 0) ? inv1 : inv2;

    __shared__ float ET[64 * 68];
    __shared__ float XA[64 * 68];
    __shared__ float XB[64 * 68];

    for (int idx = t; idx < 4096; idx += 256) {
        int r = idx >> 6, c = idx & 63;
        float e = coef * Ap[idx];
        ET[c * 68 + r] = e;
        XA[r * 68 + c] = ((r == c) ? 1.0f : 0.0f) + e;
    }
    __syncthreads();

    const int rr = (t >> 4) << 2;
    const int cc = (t & 15) << 2;
    float* bufs[2] = {XA, XB};
    for (int it = 0; it < 3; it++) {
        const float* Xin = bufs[it & 1];
        float* Xout = bufs[(it + 1) & 1];
        float acc[4][4];
        #pragma unroll
        for (int i = 0; i < 4; i++)
            #pragma unroll
            for (int j = 0; j < 4; j++)
                acc[i][j] = ((rr + i) == (cc + j)) ? 1.0f : 0.0f;
        for (int k = 0; k < 64; k++) {
            float4 e4 = *(const float4*)&ET[k * 68 + rr];
            float4 x4 = *(const float4*)&Xin[k * 68 + cc];
            float ev[4] = {e4.x, e4.y, e4.z, e4.w};
            float xv[4] = {x4.x, x4.y, x4.z, x4.w};
            #pragma unroll
            for (int i = 0; i < 4; i++)
                #pragma unroll
                for (int j = 0; j < 4; j++)
                    acc[i][j] += ev[i] * xv[j];
        }
        __syncthreads();
        #pragma unroll
        for (int i = 0; i < 4; i++)
            #pragma unroll
            for (int j = 0; j < 4; j++)
                Xout[(rr + i) * 68 + cc + j] = acc[i][j];
        __syncthreads();
    }
    const float* Xf = bufs[1];
    for (int idx = t; idx < 4096; idx += 256) {
        int r = idx >> 6, c = idx & 63;
        outp[idx] = scale * Xf[r * 68 + c];
    }
}

// ---------------------------------------------------------------------------
// One-time (per launch) bf16 conversion + MFMA-fragment packing.
// W B-frag (16x16x32): lane l holds W[n0+(l&15)][kt*32+(l>>4)*8+j], j=0..7.
// Packed: Wp[((rt*2+kt)*64+l)*8+j]  (rt = 16-row tile index, 2000 per net).
// P B-frag: lane l holds P[pt*16+(l&15)][gc*32+(l>>4)*8+j].
// Packed: Ppk[((gc*4+pt)*64+l)*8+j] (gc = 32-group chunk, 500 total).
// ---------------------------------------------------------------------------
__global__ __launch_bounds__(256) void kconv(const float* __restrict__ Wu,
                                             const float* __restrict__ Wv,
                                             const float* __restrict__ Pp,
                                             unsigned short* __restrict__ Wpu,
                                             unsigned short* __restrict__ Wpv,
                                             unsigned short* __restrict__ Ppk) {
    int idx = blockIdx.x * 256 + threadIdx.x;
    if (idx < 512000) {                         // W: 2 nets x 2000 rt x 2 kt x 64 l
        int net = idx / 256000;
        int rem = idx % 256000;
        int rt = rem >> 7;
        int r2 = rem & 127;
        int kt = r2 >> 6;
        int l  = r2 & 63;
        const float* W = net ? Wv : Wu;
        unsigned short* Wp = net ? Wpv : Wpu;
        int n  = rt * 16 + (l & 15);
        int c0 = kt * 32 + ((l >> 4) << 3);
        const float* s = W + (size_t)n * 64 + c0;
        us8 o;
        #pragma unroll
        for (int j = 0; j < 8; j++) o[j] = f2bf(s[j]);
        *(us8*)(Wp + ((size_t)(rt * 2 + kt) * 64 + l) * 8) = o;
    } else if (idx < 640000) {                  // P: 500 gc x 4 pt x 64 l
        int i2 = idx - 512000;
        int gc = i2 >> 8;
        int r  = i2 & 255;
        int pt = r >> 6;
        int l  = r & 63;
        int p  = pt * 16 + (l & 15);
        int g0 = gc * 32 + ((l >> 4) << 3);
        const float* s = Pp + (size_t)p * 16000 + g0;
        us8 o;
        #pragma unroll
        for (int j = 0; j < 8; j++) o[j] = f2bf(s[j]);
        *(us8*)(Ppk + ((size_t)(gc * 4 + pt) * 64 + l) * 8) = o;
    }
}

// ---------------------------------------------------------------------------
// Fused rhs via MFMA. 250 blocks x 512 thr (8 waves). Global wave gw owns
// (group-tile = gw>>1 of 1000, mtile = gw&1). Per wave:
//   z tiles (16b x 16 rows) for u,v,dx,dy via mfma_f32_16x16x32_bf16 with
//   a split hi/lo bf16 (fp32-accurate state), W frags streamed coalesced
//   from packed global. f = u*dx+v*dy in C-layout regs -> LDS round-trip
//   into A-layout (zero-padded to K=32) -> projection MFMA against packed
//   P frags -> per-block LDS reduce -> partials[blk] (32x64 fp32).
// kupd negates (rhs = -proj).
// ---------------------------------------------------------------------------
__global__ __launch_bounds__(512, 1) void krhs(const float* __restrict__ a,
                                               const unsigned short* __restrict__ Wpu,
                                               const unsigned short* __restrict__ Wpv,
                                               const unsigned short* __restrict__ Ppk,
                                               float* __restrict__ partials) {
    const int t = threadIdx.x;
    const int l = t & 63;
    const int w = t >> 6;                // wave in block, 0..7
    const int blk = blockIdx.x;
    const int gw = blk * 8 + w;          // 0..1999
    const int tile = gw >> 1;            // group-tile 0..999 (g0 = tile*16)
    const int mt = gw & 1;               // batch mtile
    const int net = tile >= 500;
    const int tn = net ? (tile - 500) : tile;   // net-local 16-group tile
    const unsigned short* Wp = net ? Wpv : Wpu;
    const int half = tile & 1;           // which K-half of the 32-g P chunk
    const int gc = tile >> 1;            // P chunk 0..499

    __shared__ float a_sh[32][68];
    __shared__ float fb[8][16][36];      // per-wave f tile, K=32 (+4 pad)
    __shared__ float red[8][1024];       // per-wave proj partials (16b x 64p)

    for (int i = t; i < 2048; i += 512) a_sh[i >> 6][i & 63] = a[i];
    {   // zero the complement K-half of this wave's f tile (written once)
        int b = l & 15, q = l >> 4;
        #pragma unroll
        for (int i = 0; i < 4; i++) fb[w][b][(1 - half) * 16 + q * 4 + i] = 0.f;
    }
    __syncthreads();

    // A-frags for my mtile, hi/lo bf16 split, kt = 0,1
    bf16x8 ahi[2], alo[2];
    {
        int m = mt * 16 + (l & 15);
        int k0 = (l >> 4) << 3;
        #pragma unroll
        for (int kt = 0; kt < 2; kt++) {
            us8 hv, lv;
            #pragma unroll
            for (int j = 0; j < 8; j++) {
                float x = a_sh[m][kt * 32 + k0 + j];
                unsigned short h = f2bf(x);
                hv[j] = h;
                lv[j] = f2bf(x - bf2f(h));
            }
            ahi[kt] = __builtin_bit_cast(bf16x8, hv);
            alo[kt] = __builtin_bit_cast(bf16x8, lv);
        }
    }

    // W B-frags: 4 row-blocks (u,v,dx,dy) x 2 kt, each one coalesced 1KB load
    bf16x8 wf[4][2];
    #pragma unroll
    for (int rb = 0; rb < 4; rb++) {
        int rt = rb * 500 + tn;
        #pragma unroll
        for (int kt = 0; kt < 2; kt++)
            wf[rb][kt] = *(const bf16x8*)(Wp + ((size_t)(rt * 2 + kt) * 64 + l) * 8);
    }
    // P B-frags: 4 ptiles
    bf16x8 pf[4];
    #pragma unroll
    for (int pt = 0; pt < 4; pt++)
        pf[pt] = *(const bf16x8*)(Ppk + ((size_t)(gc * 4 + pt) * 64 + l) * 8);

    // z = a @ W^T  (hi + lo)
    f32x4 z[4];
    #pragma unroll
    for (int rb = 0; rb < 4; rb++) {
        f32x4 acc = {0.f, 0.f, 0.f, 0.f};
        #pragma unroll
        for (int kt = 0; kt < 2; kt++) {
            acc = __builtin_amdgcn_mfma_f32_16x16x32_bf16(ahi[kt], wf[rb][kt], acc, 0, 0, 0);
            acc = __builtin_amdgcn_mfma_f32_16x16x32_bf16(alo[kt], wf[rb][kt], acc, 0, 0, 0);
        }
        z[rb] = acc;
    }

    // f = u*dx + v*dy, write C-layout -> LDS (my K-half)
    {
        int col = l & 15, q = l >> 4;
        #pragma unroll
        for (int r = 0; r < 4; r++) {
            float f = z[0][r] * z[2][r] + z[1][r] * z[3][r];
            fb[w][q * 4 + r][half * 16 + col] = f;
        }
    }
    __syncthreads();

    // read back in A-layout, convert bf16
    bf16x8 ff;
    {
        int b = l & 15;
        int k0 = (l >> 4) << 3;
        us8 fv;
        #pragma unroll
        for (int j = 0; j < 8; j++) fv[j] = f2bf(fb[w][b][k0 + j]);
        ff = __builtin_bit_cast(bf16x8, fv);
    }

    // projection: D[b, p] = sum_g f[b,g] * P[p,g]
    {
        int col = l & 15, q = l >> 4;
        #pragma unroll
        for (int pt = 0; pt < 4; pt++) {
            f32x4 racc = {0.f, 0.f, 0.f, 0.f};
            racc = __builtin_amdgcn_mfma_f32_16x16x32_bf16(ff, pf[pt], racc, 0, 0, 0);
            #pragma unroll
            for (int r = 0; r < 4; r++)
                red[w][(q * 4 + r) * 64 + pt * 16 + col] = racc[r];
        }
    }
    __syncthreads();

    // block partial: sum the 4 group-tiles; wave w = tnl*2 + mt
    for (int i = t; i < 2048; i += 512) {
        int b = i >> 6, p = i & 63;
        int mtb = b >> 4, bl = b & 15;
        float s = red[0 * 2 + mtb][bl * 64 + p]
                + red[1 * 2 + mtb][bl * 64 + p]
                + red[2 * 2 + mtb][bl * 64 + p]
                + red[3 * 2 + mtb][bl * 64 + p];
        partials[(size_t)blk * 2048 + i] = s;
    }
}

// ---------------------------------------------------------------------------
// Reduce partials -> rhs (negated), BDF2/Euler combine, 64x64 matvec with
// precomputed inverse, write a_{k+1}; final step writes output.
// Unchanged from round 1 (verified).
// ---------------------------------------------------------------------------
__global__ __launch_bounds__(512) void kupd(const float* __restrict__ partials,
                                            const float* __restrict__ invm,
                                            const float* __restrict__ a_new,
                                            const float* __restrict__ a_prev,
                                            const float* __restrict__ fprev,
                                            float* __restrict__ fout,
                                            float* __restrict__ a_out,
                                            const float* __restrict__ state,
                                            float* __restrict__ out,
                                            int first, int last) {
    const int bb = blockIdx.x;
    const int t = threadIdx.x;
    const int p = t & 63;
    const int q = t >> 6;
    float s = 0.f;
    for (int m = q; m < NRHS; m += 8)
        s += partials[(size_t)m * 2048 + bb * 64 + p];
    __shared__ float red[512];
    __shared__ float rrow[64];
    red[t] = s;
    __syncthreads();
    if (t < 64) {
        float f = 0.f;
        #pragma unroll
        for (int j = 0; j < 8; j++) f += red[j * 64 + t];
        f = -f;
        fout[bb * 64 + t] = f;
        float rv;
        if (first) rv = a_new[bb * 64 + t] + DTC * f;
        else       rv = 4.0f * a_new[bb * 64 + t] - a_prev[bb * 64 + t]
                      + 4.0f * DTC * f - 2.0f * DTC * fprev[bb * 64 + t];
        rrow[t] = rv;
    }
    __syncthreads();
    float acc = 0.f;
    const float* ivr = invm + p * 64 + q * 8;
    #pragma unroll
    for (int kk = 0; kk < 8; kk++) acc += ivr[kk] * rrow[q * 8 + kk];
    red[t] = acc;
    __syncthreads();
    if (t < 64) {
        float an = 0.f;
        #pragma unroll
        for (int j = 0; j < 8; j++) an += red[j * 64 + t];
        a_out[bb * 64 + t] = an;
        if (last) out[bb * 64 + t] = (an - state[bb * 64 + t]) * INV_DT_SKIP;
    }
}

// ---------------------------------------------------------------------------
extern "C" void kernel_launch(void* const* d_in, const int* in_sizes, int n_in,
                              void* d_out, int out_size, void* d_ws, size_t ws_size,
                              hipStream_t stream) {
    const float* state = (const float*)d_in[0];   // (32, 64)
    const float* Ap    = (const float*)d_in[1];   // (64, 64)
    const float* Wu    = (const float*)d_in[2];   // (32000, 64)
    const float* Wv    = (const float*)d_in[3];   // (32000, 64)
    const float* Pp    = (const float*)d_in[4];   // (64, 16000)
    float* out = (float*)d_out;
    float* ws  = (float*)d_ws;

    float* inv1 = ws;                              // 4096
    float* inv2 = ws + 4096;                       // 4096
    float* abuf = ws + 8192;                       // 3 * 2048
    float* fbuf = ws + 8192 + 3 * 2048;            // 2 * 2048
    float* partials = ws + 8192 + 5 * 2048;        // 250 * 2048 = 512000
    unsigned short* Wpu = (unsigned short*)(ws + 530432);  // 2,048,000 ushort
    unsigned short* Wpv = Wpu + 2048000;                   // 2,048,000 ushort
    unsigned short* Ppk = Wpv + 2048000;                   // 1,024,000 ushort

    hipLaunchKernelGGL(kinv, dim3(2), dim3(256), 0, stream, Ap, inv1, inv2);
    hipLaunchKernelGGL(kconv, dim3(2500), dim3(256), 0, stream,
                       Wu, Wv, Pp, Wpu, Wpv, Ppk);

    const float* aptr[51];
    aptr[0] = state;
    for (int k = 1; k <= 50; k++) aptr[k] = abuf + (size_t)((k - 1) % 3) * 2048;

    for (int k = 0; k < 50; k++) {
        hipLaunchKernelGGL(krhs, dim3(250), dim3(512), 0, stream,
                           aptr[k], Wpu, Wpv, Ppk, partials);
        hipLaunchKernelGGL(kupd, dim3(32), dim3(512), 0, stream,
                           partials,
                           (k == 0) ? inv1 : inv2,
                           aptr[k],
                           (k >= 1) ? aptr[k - 1] : state,
                           fbuf + (size_t)((k + 1) & 1) * 2048,
                           fbuf + (size_t)(k & 1) * 2048,
                           (float*)aptr[k + 1],
                           state, out,
                           (k == 0) ? 1 : 0,
                           (k == 49) ? 1 : 0);
    }
}